// Round 1
// baseline (10.986 us; speedup 1.0000x reference)
//
#include <hip/hip_runtime.h>
#include <hip/hip_bf16.h>
#include <math.h>

// Problem geometry (fixed by the reference):
//   flow: (B=64, T=64, H=64, W=64, 2) f32; only flow[:, 63, 32, 32, :] used.
//   F = 256. GRU with h0=0  =>  gh = b_hh (W_hh unused).
//   y1 = relu(h @ W1.T + b1)   (128x256)
//   y2 = tanh(y1 @ W2.T + b2)  (2x128)
//   out = y2 @ W3.T + b3       (2x2)   -> (64, 2) f32
#define FDIM 256

__global__ __launch_bounds__(256) void flow_model_kernel(
    const float* __restrict__ flow,
    const float* __restrict__ W_ih, const float* __restrict__ b_ih,
    const float* __restrict__ b_hh,
    const float* __restrict__ W1,   const float* __restrict__ b1,
    const float* __restrict__ W2,   const float* __restrict__ b2,
    const float* __restrict__ W3,   const float* __restrict__ b3,
    float* __restrict__ out)
{
    const int b = blockIdx.x;   // batch row, 0..63
    const int t = threadIdx.x;  // 0..255

    __shared__ __align__(16) float h_s[FDIM];
    __shared__ __align__(16) float y1_s[128];

    // x = flow[b, 63, 32, 32, :]
    // strides: b:64*64*64*2=524288, t:64*64*2=8192, h:64*2=128, w:2
    const size_t base = (size_t)b * 524288 + (size_t)63 * 8192 + 32 * 128 + 32 * 2;
    const float x0 = flow[base + 0];
    const float x1 = flow[base + 1];

    // ---- GRU gates (h0 = 0 so hidden-side pre-activation is just b_hh) ----
    {
        const int i = t;
        const float rx = W_ih[2 * i + 0]            * x0 + W_ih[2 * i + 1]            * x1 + b_ih[i];
        const float zx = W_ih[2 * (FDIM + i) + 0]   * x0 + W_ih[2 * (FDIM + i) + 1]   * x1 + b_ih[FDIM + i];
        const float nx = W_ih[2 * (2*FDIM + i) + 0] * x0 + W_ih[2 * (2*FDIM + i) + 1] * x1 + b_ih[2*FDIM + i];
        const float r = 1.0f / (1.0f + expf(-(rx + b_hh[i])));
        const float z = 1.0f / (1.0f + expf(-(zx + b_hh[FDIM + i])));
        const float n = tanhf(nx + r * b_hh[2*FDIM + i]);
        h_s[i] = (1.0f - z) * n;
    }
    __syncthreads();

    // ---- y1 = relu(h @ W1.T + b1): 128 outputs, 2 threads per output ----
    {
        const int j    = t >> 1;   // output index 0..127
        const int half = t & 1;    // which half of the 256-dot
        const float4* wrow = reinterpret_cast<const float4*>(W1 + j * FDIM + half * 128);
        const float4* hv   = reinterpret_cast<const float4*>(h_s + half * 128);
        float p = 0.0f;
        #pragma unroll
        for (int k = 0; k < 32; ++k) {
            const float4 w = wrow[k];
            const float4 h = hv[k];
            p += w.x * h.x + w.y * h.y + w.z * h.z + w.w * h.w;
        }
        p += __shfl_xor(p, 1);  // combine the two halves (adjacent lanes)
        if (half == 0) y1_s[j] = fmaxf(p + b1[j], 0.0f);
    }
    __syncthreads();

    // ---- y2 = tanh(y1 @ W2.T + b2); out = y2 @ W3.T + b3 ----
    if (t < 64) {
        // each lane covers k = t and k = t + 64 of the 128-dot, for both outputs
        float p0 = W2[t]       * y1_s[t] + W2[64 + t]        * y1_s[64 + t];
        float p1 = W2[128 + t] * y1_s[t] + W2[128 + 64 + t]  * y1_s[64 + t];
        #pragma unroll
        for (int off = 32; off > 0; off >>= 1) {
            p0 += __shfl_down(p0, off);
            p1 += __shfl_down(p1, off);
        }
        if (t == 0) {
            const float y20 = tanhf(p0 + b2[0]);
            const float y21 = tanhf(p1 + b2[1]);
            out[2 * b + 0] = W3[0] * y20 + W3[1] * y21 + b3[0];
            out[2 * b + 1] = W3[2] * y20 + W3[3] * y21 + b3[1];
        }
    }
}

extern "C" void kernel_launch(void* const* d_in, const int* in_sizes, int n_in,
                              void* d_out, int out_size, void* d_ws, size_t ws_size,
                              hipStream_t stream) {
    // setup_inputs() order:
    // 0 flow, 1 W_ih, 2 b_ih, 3 W_hh (unused: h0=0), 4 b_hh,
    // 5 W1, 6 b1, 7 W2, 8 b2, 9 W3, 10 b3
    const float* flow = (const float*)d_in[0];
    const float* W_ih = (const float*)d_in[1];
    const float* b_ih = (const float*)d_in[2];
    const float* b_hh = (const float*)d_in[4];
    const float* W1   = (const float*)d_in[5];
    const float* b1   = (const float*)d_in[6];
    const float* W2   = (const float*)d_in[7];
    const float* b2   = (const float*)d_in[8];
    const float* W3   = (const float*)d_in[9];
    const float* b3   = (const float*)d_in[10];
    float* out = (float*)d_out;

    flow_model_kernel<<<64, 256, 0, stream>>>(
        flow, W_ih, b_ih, b_hh, W1, b1, W2, b2, W3, b3, out);
}

// Round 2
// 10.602 us; speedup vs baseline: 1.0362x; 1.0362x over previous
//
#include <hip/hip_runtime.h>
#include <hip/hip_bf16.h>
#include <math.h>

// Problem geometry (fixed by the reference):
//   flow: (B=64, T=64, H=64, W=64, 2) f32; only flow[:, 63, 32, 32, :] used.
//   F = 256. GRU with h0=0  =>  gh = b_hh (W_hh unused).
//   y1 = relu(h @ W1.T + b1)   (128x256)
//   y2 = tanh(y1 @ W2.T + b2)  (2x128)
//   out = y2 @ W3.T + b3       (2x2)   -> (64, 2) f32
//
// Latency-bound microkernel: 64 blocks x 256 threads, 1 block/CU.
// All global loads are issued at kernel entry so the HBM-miss latencies
// (x, W_ih, W1) overlap instead of serializing across the barrier.
#define FDIM 256

__device__ __forceinline__ float fast_sigmoid(float v) {
    // native v_exp_f32; |rel err| ~1e-6, threshold is 3.4e-3
    return 1.0f / (1.0f + __expf(-v));
}
__device__ __forceinline__ float fast_tanh(float v) {
    return 2.0f / (1.0f + __expf(-2.0f * v)) - 1.0f;
}

__global__ __launch_bounds__(256) void flow_model_kernel(
    const float* __restrict__ flow,
    const float* __restrict__ W_ih, const float* __restrict__ b_ih,
    const float* __restrict__ b_hh,
    const float* __restrict__ W1,   const float* __restrict__ b1,
    const float* __restrict__ W2,   const float* __restrict__ b2,
    const float* __restrict__ W3,   const float* __restrict__ b3,
    float* __restrict__ out)
{
    const int b = blockIdx.x;   // batch row, 0..63
    const int t = threadIdx.x;  // 0..255

    __shared__ __align__(16) float h_s[FDIM];
    __shared__ __align__(16) float y1_s[128];

    // ---------- issue ALL independent global loads up front ----------
    // x = flow[b, 63, 32, 32, :]  (strides: b 524288, t 8192, h 128, w 2)
    const size_t base = (size_t)b * 524288 + (size_t)63 * 8192 + 32 * 128 + 32 * 2;
    const float x0 = flow[base + 0];
    const float x1 = flow[base + 1];

    // W_ih rows for this thread's 3 gate features (+ biases)
    const float wr0 = W_ih[2 * t + 0],              wr1 = W_ih[2 * t + 1];
    const float wz0 = W_ih[2 * (FDIM + t) + 0],     wz1 = W_ih[2 * (FDIM + t) + 1];
    const float wn0 = W_ih[2 * (2 * FDIM + t) + 0], wn1 = W_ih[2 * (2 * FDIM + t) + 1];
    const float bir = b_ih[t], biz = b_ih[FDIM + t], bin_ = b_ih[2 * FDIM + t];
    const float bhr = b_hh[t], bhz = b_hh[FDIM + t], bhn = b_hh[2 * FDIM + t];

    // W1 fragment: thread t covers output j = t>>1, half = t&1 of the 256-dot.
    // 32 float4 = 128 VGPRs; issued now so the cold HBM miss overlaps gate math.
    const int j    = t >> 1;
    const int half = t & 1;
    const float4* __restrict__ wrow =
        reinterpret_cast<const float4*>(W1 + j * FDIM + half * 128);
    float4 w[32];
    #pragma unroll
    for (int k = 0; k < 32; ++k) w[k] = wrow[k];
    const float b1j = b1[j];

    // W2/W3/b2/b3 for the final stage (first wave only)
    float w2a = 0.f, w2b = 0.f, w2c = 0.f, w2d = 0.f;
    float b2_0 = 0.f, b2_1 = 0.f;
    float w30 = 0.f, w31 = 0.f, w32_ = 0.f, w33 = 0.f, b3_0 = 0.f, b3_1 = 0.f;
    if (t < 64) {
        w2a = W2[t];        w2b = W2[64 + t];
        w2c = W2[128 + t];  w2d = W2[192 + t];
        b2_0 = b2[0]; b2_1 = b2[1];
        w30 = W3[0]; w31 = W3[1]; w32_ = W3[2]; w33 = W3[3];
        b3_0 = b3[0]; b3_1 = b3[1];
    }

    // ---------- GRU gates (h0 = 0 so hidden-side pre-activation = b_hh) ----------
    {
        const float rx = wr0 * x0 + wr1 * x1 + bir;
        const float zx = wz0 * x0 + wz1 * x1 + biz;
        const float nx = wn0 * x0 + wn1 * x1 + bin_;
        const float r = fast_sigmoid(rx + bhr);
        const float z = fast_sigmoid(zx + bhz);
        const float n = fast_tanh(nx + r * bhn);
        h_s[t] = (1.0f - z) * n;
    }
    __syncthreads();

    // ---------- y1 = relu(h @ W1.T + b1): 2 threads per output ----------
    {
        const float4* __restrict__ hv =
            reinterpret_cast<const float4*>(h_s + half * 128);
        float p = 0.0f;
        #pragma unroll
        for (int k = 0; k < 32; ++k) {
            const float4 h = hv[k];
            p += w[k].x * h.x + w[k].y * h.y + w[k].z * h.z + w[k].w * h.w;
        }
        p += __shfl_xor(p, 1);  // combine the two halves (adjacent lanes)
        if (half == 0) y1_s[j] = fmaxf(p + b1j, 0.0f);
    }
    __syncthreads();

    // ---------- y2 = tanh(y1 @ W2.T + b2); out = y2 @ W3.T + b3 ----------
    if (t < 64) {
        float p0 = w2a * y1_s[t] + w2b * y1_s[64 + t];
        float p1 = w2c * y1_s[t] + w2d * y1_s[64 + t];
        #pragma unroll
        for (int off = 32; off > 0; off >>= 1) {
            p0 += __shfl_down(p0, off);
            p1 += __shfl_down(p1, off);
        }
        if (t == 0) {
            const float y20 = fast_tanh(p0 + b2_0);
            const float y21 = fast_tanh(p1 + b2_1);
            out[2 * b + 0] = w30 * y20 + w31 * y21 + b3_0;
            out[2 * b + 1] = w32_ * y20 + w33 * y21 + b3_1;
        }
    }
}

extern "C" void kernel_launch(void* const* d_in, const int* in_sizes, int n_in,
                              void* d_out, int out_size, void* d_ws, size_t ws_size,
                              hipStream_t stream) {
    // setup_inputs() order:
    // 0 flow, 1 W_ih, 2 b_ih, 3 W_hh (unused: h0=0), 4 b_hh,
    // 5 W1, 6 b1, 7 W2, 8 b2, 9 W3, 10 b3
    const float* flow = (const float*)d_in[0];
    const float* W_ih = (const float*)d_in[1];
    const float* b_ih = (const float*)d_in[2];
    const float* b_hh = (const float*)d_in[4];
    const float* W1   = (const float*)d_in[5];
    const float* b1   = (const float*)d_in[6];
    const float* W2   = (const float*)d_in[7];
    const float* b2   = (const float*)d_in[8];
    const float* W3   = (const float*)d_in[9];
    const float* b3   = (const float*)d_in[10];
    float* out = (float*)d_out;

    flow_model_kernel<<<64, 256, 0, stream>>>(
        flow, W_ih, b_ih, b_hh, W1, b1, W2, b2, W3, b3, out);
}